// Round 2
// baseline (199.925 us; speedup 1.0000x reference)
//
#include <hip/hip_runtime.h>
#include <math.h>

// ClockworkGatedRNN collapse:
//   The scan's per-step update `new = gating(x_t)` never reads h, so the
//   carried state for group g is just the gating evaluated at the LAST
//   timestep t with t % p == 0:  t_g = 2047 - (2047 & (p-1)) for p=1,2,4,8
//   -> t = 2047, 2046, 2044, 2040.
//   hT[:, g*128:(g+1)*128] = gating(X[:, t_g, :] @ W[:, g*128:(g+1)*128] + b_g)
//   gating(x) = z*softplus(x*tanh((x*x)@Ug)) + (1-z)*x,
//       z = clip(0.2*(x + x@U) + 0.5, 0, 1)
//   W_gate / b_gate are dead inputs (x_gate is computed but never used).

#define TT    2048
#define DIN   256
#define DOUT  512
#define NSUB  128
#define BDIM  64
#define ROWS  8     // batch rows per block

__global__ __launch_bounds__(256)
void cgrnn_collapsed_kernel(const float* __restrict__ X,
                            const float* __restrict__ W,
                            const float* __restrict__ bias,
                            const float* __restrict__ clock_u,
                            const float* __restrict__ clock_g,
                            float* __restrict__ out)
{
    const int g   = blockIdx.x & 3;       // period group 0..3
    const int rb  = blockIdx.x >> 2;      // row block 0..7
    const int r0  = rb * ROWS;
    const int tid = threadIdx.x;
    const int c4  = tid & 31;             // which float4 along the 128 cols
    const int r   = tid >> 5;             // row within block (0..7)
    const int c   = c4 * 4;

    const int p  = 1 << g;
    const int t  = 2047 - (2047 & (p - 1));   // last update time for this group

    __shared__ float Xs[ROWS][DIN];           // 8 KB
    __shared__ float xs[ROWS][NSUB + 4];      // padded x_sub, ~4.2 KB

    // ---- stage X rows for this block's batch rows at timestep t ----
    // X[b][t][i] flat: (b*TT + t)*DIN + i
    {
        for (int idx = tid; idx < ROWS * (DIN / 4); idx += 256) {
            const int rr = idx >> 6;          // / (DIN/4)
            const int ii = idx & 63;
            const float4 v = *reinterpret_cast<const float4*>(
                X + ((size_t)(r0 + rr) * TT + t) * DIN + ii * 4);
            *reinterpret_cast<float4*>(&Xs[rr][ii * 4]) = v;
        }
    }
    __syncthreads();

    // ---- phase A: x_sub[r][c..c+3] = Xs[r][:] @ W[:, g*128 + c..c+3] + b ----
    float a0, a1, a2, a3;
    {
        const float* bb = bias + g * NSUB + c;
        a0 = bb[0]; a1 = bb[1]; a2 = bb[2]; a3 = bb[3];
        const float* Wc = W + g * NSUB + c;
#pragma unroll 16
        for (int k = 0; k < DIN; ++k) {
            const float xk = Xs[r][k];
            const float4 wv = *reinterpret_cast<const float4*>(Wc + (size_t)k * DOUT);
            a0 = fmaf(xk, wv.x, a0);
            a1 = fmaf(xk, wv.y, a1);
            a2 = fmaf(xk, wv.z, a2);
            a3 = fmaf(xk, wv.w, a3);
        }
        xs[r][c + 0] = a0;
        xs[r][c + 1] = a1;
        xs[r][c + 2] = a2;
        xs[r][c + 3] = a3;
    }
    __syncthreads();

    // ---- phase B: k = x_sub @ u ; q = (x_sub^2) @ u_gate ----
    float k0 = 0.f, k1 = 0.f, k2 = 0.f, k3 = 0.f;
    float q0 = 0.f, q1 = 0.f, q2 = 0.f, q3 = 0.f;
    {
        const float* ub = clock_u + (size_t)g * NSUB * NSUB + c;
        const float* gb = clock_g + (size_t)g * NSUB * NSUB + c;
#pragma unroll 8
        for (int j = 0; j < NSUB; ++j) {
            const float xv  = xs[r][j];
            const float xv2 = xv * xv;
            const float4 uv = *reinterpret_cast<const float4*>(ub + j * NSUB);
            const float4 gv = *reinterpret_cast<const float4*>(gb + j * NSUB);
            k0 = fmaf(xv, uv.x, k0);  k1 = fmaf(xv, uv.y, k1);
            k2 = fmaf(xv, uv.z, k2);  k3 = fmaf(xv, uv.w, k3);
            q0 = fmaf(xv2, gv.x, q0); q1 = fmaf(xv2, gv.y, q1);
            q2 = fmaf(xv2, gv.z, q2); q3 = fmaf(xv2, gv.w, q3);
        }
    }

    // ---- elementwise gating ----
    float xr[4] = {a0, a1, a2, a3};
    float kk[4] = {k0, k1, k2, k3};
    float qq[4] = {q0, q1, q2, q3};
    float4 res;
    float* rp = reinterpret_cast<float*>(&res);
#pragma unroll
    for (int i = 0; i < 4; ++i) {
        const float x  = xr[i];
        // z = clip(0.2*(x + k) + 0.5, 0, 1)
        float z = 0.2f * (x + kk[i]) + 0.5f;
        z = fminf(fmaxf(z, 0.0f), 1.0f);
        const float zg = tanhf(qq[i]);
        const float a  = x * zg;
        // stable softplus: max(a,0) + log1p(exp(-|a|))
        const float zo = fmaxf(a, 0.0f) + log1pf(expf(-fabsf(a)));
        rp[i] = z * zo + (1.0f - z) * x;
    }

    // ---- store: out[b][g*128 + c .. +3], out is (64, 512) row-major ----
    *reinterpret_cast<float4*>(out + (size_t)(r0 + r) * DOUT + g * NSUB + c) = res;
}

extern "C" void kernel_launch(void* const* d_in, const int* in_sizes, int n_in,
                              void* d_out, int out_size, void* d_ws, size_t ws_size,
                              hipStream_t stream)
{
    const float* X       = (const float*)d_in[0];
    const float* W       = (const float*)d_in[1];
    const float* bias    = (const float*)d_in[2];
    // d_in[3] = W_gate, d_in[4] = b_gate : dead inputs
    const float* clock_u = (const float*)d_in[5];
    const float* clock_g = (const float*)d_in[6];
    float* out           = (float*)d_out;

    dim3 grid(4 * (BDIM / ROWS));   // 32 blocks
    dim3 block(256);
    cgrnn_collapsed_kernel<<<grid, block, 0, stream>>>(X, W, bias, clock_u, clock_g, out);
}

// Round 8
// 173.870 us; speedup vs baseline: 1.1499x; 1.1499x over previous
//
#include <hip/hip_runtime.h>
#include <math.h>

// ClockworkGatedRNN collapse:
//   The scan's per-step update `new = gating(x_t)` never reads h, so the
//   carried state for group g is the gating evaluated at the LAST timestep
//   t with t % p == 0:  t_g = 2047 - (2047 & (p-1)), p = 1,2,4,8
//   -> t = 2047, 2046, 2044, 2040.
//   hT[:, g*128:(g+1)*128] = gating(X[:, t_g, :] @ W[:, g*128:(g+1)*128] + b_g)
//   gating(x) = z*softplus(x*tanh((x*x)@Ug)) + (1-z)*x,
//       z = clip(0.2*(x + x@U) + 0.5, 0, 1)
//   W_gate / b_gate are dead inputs (x_gate computed but never used).
//
// Decomposition: 256 blocks = (b 0..63) x (g 0..3), one block per CU.
// 256 threads = (c4 0..31) x (h 0..7): 8-way K-split per dot product,
// LDS tree reduce. Shortens dependent-FMA chains 256 -> 32 and puts all
// cold global loads of a thread in flight simultaneously.

#define TT    2048
#define DIN   256
#define DOUT  512
#define NSUB  128

__global__ __launch_bounds__(256)
void cgrnn_collapsed_kernel(const float* __restrict__ X,
                            const float* __restrict__ W,
                            const float* __restrict__ bias,
                            const float* __restrict__ clock_u,
                            const float* __restrict__ clock_g,
                            float* __restrict__ out)
{
    const int g   = blockIdx.x & 3;
    const int b   = blockIdx.x >> 2;          // batch row 0..63
    const int tid = threadIdx.x;
    const int c4  = tid & 31;                 // float4 column group (c = c4*4)
    const int h   = tid >> 5;                 // K-slice 0..7
    const int t   = 2047 - (2047 & ((1 << g) - 1));

    __shared__ float Xr[DIN];                 // staged X row (1 KB)
    __shared__ float xs[NSUB];                // x_sub
    __shared__ float partA[8][NSUB];          // phase-A partials (4 KB)
    __shared__ float partK[8][NSUB];
    __shared__ float partQ[8][NSUB];

    // ---- stage X[b, t, :] (256 floats) ----
    if (tid < DIN / 4) {
        reinterpret_cast<float4*>(Xr)[tid] =
            reinterpret_cast<const float4*>(X + ((size_t)b * TT + t) * DIN)[tid];
    }
    __syncthreads();

    // ---- phase A partial: 32 k's per thread ----
    {
        float a0 = 0.f, a1 = 0.f, a2 = 0.f, a3 = 0.f;
        const float* Wc = W + g * NSUB + c4 * 4;
#pragma unroll
        for (int kk = 0; kk < 32; ++kk) {
            const int k = h * 32 + kk;
            const float xk = Xr[k];
            const float4 wv = *reinterpret_cast<const float4*>(Wc + (size_t)k * DOUT);
            a0 = fmaf(xk, wv.x, a0);
            a1 = fmaf(xk, wv.y, a1);
            a2 = fmaf(xk, wv.z, a2);
            a3 = fmaf(xk, wv.w, a3);
        }
        partA[h][c4 * 4 + 0] = a0;
        partA[h][c4 * 4 + 1] = a1;
        partA[h][c4 * 4 + 2] = a2;
        partA[h][c4 * 4 + 3] = a3;
    }
    __syncthreads();

    // ---- reduce to x_sub ----
    if (tid < NSUB) {
        float s = bias[g * NSUB + tid];
#pragma unroll
        for (int hh = 0; hh < 8; ++hh) s += partA[hh][tid];
        xs[tid] = s;
    }
    __syncthreads();

    // ---- phase B partial: k = x_sub @ u ; q = x_sub^2 @ u_gate (16 j's each) ----
    {
        float k0 = 0.f, k1 = 0.f, k2 = 0.f, k3 = 0.f;
        float q0 = 0.f, q1 = 0.f, q2 = 0.f, q3 = 0.f;
        const float* ub = clock_u + (size_t)g * NSUB * NSUB + c4 * 4;
        const float* gb = clock_g + (size_t)g * NSUB * NSUB + c4 * 4;
#pragma unroll
        for (int jj = 0; jj < 16; ++jj) {
            const int j = h * 16 + jj;
            const float xv  = xs[j];
            const float xv2 = xv * xv;
            const float4 uv = *reinterpret_cast<const float4*>(ub + j * NSUB);
            const float4 gv = *reinterpret_cast<const float4*>(gb + j * NSUB);
            k0 = fmaf(xv, uv.x, k0);  k1 = fmaf(xv, uv.y, k1);
            k2 = fmaf(xv, uv.z, k2);  k3 = fmaf(xv, uv.w, k3);
            q0 = fmaf(xv2, gv.x, q0); q1 = fmaf(xv2, gv.y, q1);
            q2 = fmaf(xv2, gv.z, q2); q3 = fmaf(xv2, gv.w, q3);
        }
        partK[h][c4 * 4 + 0] = k0;  partQ[h][c4 * 4 + 0] = q0;
        partK[h][c4 * 4 + 1] = k1;  partQ[h][c4 * 4 + 1] = q1;
        partK[h][c4 * 4 + 2] = k2;  partQ[h][c4 * 4 + 2] = q2;
        partK[h][c4 * 4 + 3] = k3;  partQ[h][c4 * 4 + 3] = q3;
    }
    __syncthreads();

    // ---- final reduce + gating + store ----
    if (tid < NSUB) {
        float ks = 0.f, qs = 0.f;
#pragma unroll
        for (int hh = 0; hh < 8; ++hh) { ks += partK[hh][tid]; qs += partQ[hh][tid]; }
        const float x = xs[tid];
        float z = 0.2f * (x + ks) + 0.5f;
        z = fminf(fmaxf(z, 0.0f), 1.0f);
        const float zg = tanhf(qs);
        const float a  = x * zg;
        const float zo = fmaxf(a, 0.0f) + log1pf(expf(-fabsf(a)));  // stable softplus
        out[(size_t)b * DOUT + g * NSUB + tid] = z * zo + (1.0f - z) * x;
    }
}

extern "C" void kernel_launch(void* const* d_in, const int* in_sizes, int n_in,
                              void* d_out, int out_size, void* d_ws, size_t ws_size,
                              hipStream_t stream)
{
    const float* X       = (const float*)d_in[0];
    const float* W       = (const float*)d_in[1];
    const float* bias    = (const float*)d_in[2];
    // d_in[3] = W_gate, d_in[4] = b_gate : dead inputs
    const float* clock_u = (const float*)d_in[5];
    const float* clock_g = (const float*)d_in[6];
    float* out           = (float*)d_out;

    dim3 grid(256);   // (b 0..63) x (g 0..3), one block per CU
    dim3 block(256);
    cgrnn_collapsed_kernel<<<grid, block, 0, stream>>>(X, W, bias, clock_u, clock_g, out);
}